// Round 1
// baseline (161.088 us; speedup 1.0000x reference)
//
#include <hip/hip_runtime.h>
#include <hip/hip_bf16.h>
#include <stdint.h>

// Problem dims (fixed by reference)
#define HH 224
#define WW 224
#define CC 1024
#define BB 256
#define KK (HH*WW)            // 50176
#define EPSILON_F 0.001f
#define LOG2E 1.4426950408889634f
#define INVN (1.0f/50176.0f)
// clip(v,±2000)/N == clip(v/N, ±2000/N) since 1/N > 0
#define CLAMP_V (2000.0f/50176.0f)

// K-split: 32 chunks of 1568 = 7 rows of 224. Each 32-wide K-step lies in one image row.
#define KCHUNKS 32
#define ROWS_PER_CHUNK 7
#define STEPS_PER_ROW 7       // 224/32

#define LDS_STRIDE 40         // 32 bf16 + 8 pad (80B = 20 banks -> <=2-way, free)

typedef __bf16 bf16x8 __attribute__((ext_vector_type(8)));
typedef float  f32x4  __attribute__((ext_vector_type(4)));

__global__ __launch_bounds__(256)
void blob_gemm_kernel(const float* __restrict__ x,
                      const float* __restrict__ pos,
                      const float* __restrict__ sig,
                      const float* __restrict__ cwt,
                      const float* __restrict__ xs,
                      const float* __restrict__ ys,
                      float* __restrict__ out) {
    __shared__ __bf16 As[128 * LDS_STRIDE];   // A-tile: 128 m-rows x 32 k (bf16)
    __shared__ __bf16 Bs[128 * LDS_STRIDE];   // B^T-tile: 128 c-rows x 32 k (bf16)
    __shared__ float  xrow[WW];               // x_axis (xs row 0), reused every row
    __shared__ float  ycol[ROWS_PER_CHUNK];   // y_axis values for this chunk's rows

    const int tid  = threadIdx.x;
    const int wave = tid >> 6;
    const int lane = tid & 63;

    const int c0 = blockIdx.x * 128;              // N-tile (8)
    const int m0 = blockIdx.y * 128;              // M-tile (2)
    const int k0 = blockIdx.z * (ROWS_PER_CHUNK * WW);  // K-chunk (32)

    // ---- preload axis values ----
    if (tid < WW) xrow[tid] = xs[tid];                       // xs[0*W + w] = x_axis[w]
    if (tid >= WW && tid < WW + ROWS_PER_CHUNK) {
        int r = tid - WW;
        int h = blockIdx.z * ROWS_PER_CHUNK + r;
        ycol[r] = ys[h * WW];                                // ys[h*W + 0] = y_axis[h]
    }

    // ---- per-thread curve params: this thread generates 2 groups of 8 curve elems/step ----
    // group g covers LDS c-row cidx = (g*256 + tid)/4, k-octet q = tid&3
    const int q    = tid & 3;
    const int cr0  = tid >> 2;          // 0..63
    float A2[2], S2[2], P1[2], EYC[2];  // EYC computed per image-row
    float P0[2];
#pragma unroll
    for (int g = 0; g < 2; ++g) {
        int cidx = (g << 6) + cr0;      // (g*256+tid)>>2
        int c = c0 + cidx;
        float s  = sig[c];
        float w  = cwt[c];
        float s2 = s * s;
        A2[g] = w / (6.283185307179586f * s2 + EPSILON_F) * INVN;  // factor*cw/N
        S2[g] = LOG2E / (2.0f * s2 + EPSILON_F);                   // log2e / two_sig2
        P0[g] = pos[2 * c];       // y position
        P1[g] = pos[2 * c + 1];   // x position
    }

    // LDS write pointers (A-stage chunk idx = it*256+tid -> row idx>>2, octet idx&3)
    __bf16* as_w0 = As + cr0 * LDS_STRIDE + q * 8;
    __bf16* as_w1 = As + (64 + cr0) * LDS_STRIDE + q * 8;
    __bf16* bs_w0 = Bs + cr0 * LDS_STRIDE + q * 8;
    __bf16* bs_w1 = Bs + (64 + cr0) * LDS_STRIDE + q * 8;

    // A-stage global base (fp32 x, converted in-register)
    const float* ag0 = x + (size_t)(m0 + cr0) * KK + k0 + q * 8;
    const float* ag1 = x + (size_t)(m0 + 64 + cr0) * KK + k0 + q * 8;

    // wave quadrant: 2x2 waves of 64x64
    const int wm = (wave & 1) * 64;
    const int wn = (wave >> 1) * 64;
    const int fl = lane & 15;
    const int fk = (lane >> 4) * 8;
    const __bf16* ar = As + (wm + fl) * LDS_STRIDE + fk;
    const __bf16* br = Bs + (wn + fl) * LDS_STRIDE + fk;

    f32x4 acc[4][4];
#pragma unroll
    for (int i = 0; i < 4; ++i)
#pragma unroll
        for (int j = 0; j < 4; ++j) acc[i][j] = (f32x4){0.f, 0.f, 0.f, 0.f};

    __syncthreads();  // xrow/ycol ready

#pragma unroll 1
    for (int r = 0; r < ROWS_PER_CHUNK; ++r) {
        const float ysv = ycol[r];
        {
            float dy0 = ysv - P0[0]; EYC[0] = dy0 * dy0 * S2[0];
            float dy1 = ysv - P0[1]; EYC[1] = dy1 * dy1 * S2[1];
        }
#pragma unroll 1
        for (int wb = 0; wb < STEPS_PER_ROW; ++wb) {
            const int kb = r * WW + wb * 32;  // offset within chunk

            // issue A loads early (fp32)
            float4 a00 = *(const float4*)(ag0 + kb);
            float4 a01 = *(const float4*)(ag0 + kb + 4);
            float4 a10 = *(const float4*)(ag1 + kb);
            float4 a11 = *(const float4*)(ag1 + kb + 4);

            // x-axis values for this thread's k-octet (same for both groups)
            float4 xv0 = *(const float4*)(xrow + wb * 32 + q * 8);
            float4 xv1 = *(const float4*)(xrow + wb * 32 + q * 8 + 4);
            float xv[8] = {xv0.x, xv0.y, xv0.z, xv0.w, xv1.x, xv1.y, xv1.z, xv1.w};

            // generate 16 curve values -> bf16
            union { __bf16 h[8]; uint4 u; } cv0, cv1;
#pragma unroll
            for (int i = 0; i < 8; ++i) {
                float dx0 = xv[i] - P1[0];
                float t0  = __builtin_fmaf(dx0 * S2[0], dx0, EYC[0]);
                float v0  = __builtin_amdgcn_exp2f(-t0) * A2[0];
                v0 = fminf(fmaxf(v0, -CLAMP_V), CLAMP_V);
                cv0.h[i] = (__bf16)v0;
                float dx1 = xv[i] - P1[1];
                float t1  = __builtin_fmaf(dx1 * S2[1], dx1, EYC[1]);
                float v1  = __builtin_amdgcn_exp2f(-t1) * A2[1];
                v1 = fminf(fmaxf(v1, -CLAMP_V), CLAMP_V);
                cv1.h[i] = (__bf16)v1;
            }

            // convert A to bf16
            union { __bf16 h[8]; uint4 u; } av0, av1;
            av0.h[0] = (__bf16)a00.x; av0.h[1] = (__bf16)a00.y;
            av0.h[2] = (__bf16)a00.z; av0.h[3] = (__bf16)a00.w;
            av0.h[4] = (__bf16)a01.x; av0.h[5] = (__bf16)a01.y;
            av0.h[6] = (__bf16)a01.z; av0.h[7] = (__bf16)a01.w;
            av1.h[0] = (__bf16)a10.x; av1.h[1] = (__bf16)a10.y;
            av1.h[2] = (__bf16)a10.z; av1.h[3] = (__bf16)a10.w;
            av1.h[4] = (__bf16)a11.x; av1.h[5] = (__bf16)a11.y;
            av1.h[6] = (__bf16)a11.z; av1.h[7] = (__bf16)a11.w;

            __syncthreads();  // previous iteration's fragment reads done
            *(uint4*)bs_w0 = cv0.u;
            *(uint4*)bs_w1 = cv1.u;
            *(uint4*)as_w0 = av0.u;
            *(uint4*)as_w1 = av1.u;
            __syncthreads();

            // fragments + 16 MFMAs
            bf16x8 af[4], bf[4];
#pragma unroll
            for (int i = 0; i < 4; ++i) {
                af[i] = *(const bf16x8*)(ar + i * 16 * LDS_STRIDE);
                bf[i] = *(const bf16x8*)(br + i * 16 * LDS_STRIDE);
            }
#pragma unroll
            for (int mi = 0; mi < 4; ++mi)
#pragma unroll
                for (int ni = 0; ni < 4; ++ni)
                    acc[mi][ni] = __builtin_amdgcn_mfma_f32_16x16x32_bf16(
                        af[mi], bf[ni], acc[mi][ni], 0, 0, 0);
        }
    }

    // epilogue: C/D layout col=lane&15, row=(lane>>4)*4+reg  -> atomicAdd (K-split)
    const int orow = (lane >> 4) * 4;
#pragma unroll
    for (int mi = 0; mi < 4; ++mi) {
        int m = m0 + wm + mi * 16 + orow;
#pragma unroll
        for (int ni = 0; ni < 4; ++ni) {
            int c = c0 + wn + ni * 16 + fl;
#pragma unroll
            for (int v = 0; v < 4; ++v)
                atomicAdd(out + (size_t)(m + v) * CC + c, acc[mi][ni][v]);
        }
    }
}

extern "C" void kernel_launch(void* const* d_in, const int* in_sizes, int n_in,
                              void* d_out, int out_size, void* d_ws, size_t ws_size,
                              hipStream_t stream) {
    const float* x   = (const float*)d_in[0];
    const float* pos = (const float*)d_in[1];
    const float* sg  = (const float*)d_in[2];
    const float* cw  = (const float*)d_in[3];
    const float* xs  = (const float*)d_in[4];
    const float* ys  = (const float*)d_in[5];
    float* out = (float*)d_out;

    // K-split partials accumulate via atomicAdd -> zero output first
    hipMemsetAsync(out, 0, (size_t)BB * CC * sizeof(float), stream);

    dim3 grid(CC / 128, BB / 128, KCHUNKS);  // (8, 2, 32) = 512 blocks
    blob_gemm_kernel<<<grid, 256, 0, stream>>>(x, pos, sg, cw, xs, ys, out);
}